// Round 2
// baseline (76.842 us; speedup 1.0000x reference)
//
#include <hip/hip_runtime.h>

#define IMG_H 256
#define IMG_W 256
#define ROWS 16
#define STRIPS (IMG_H / ROWS)    // 16 strips per image
#define NIMG 128

// lane-shift via bpermute (addr precomputed once)
__device__ __forceinline__ float pullf(int addr, float v) {
    return __int_as_float(__builtin_amdgcn_ds_bpermute(addr, __float_as_int(v)));
}

__device__ __forceinline__ float4 f4fma(float w, float4 a, float4 b) {
    return make_float4(fmaf(w, a.x, b.x), fmaf(w, a.y, b.y),
                       fmaf(w, a.z, b.z), fmaf(w, a.w, b.w));
}

__device__ __forceinline__ float ssim1(float mu1, float mu2, float spp, float stt, float spt) {
    const float C1 = 1e-4f, C2 = 9e-4f;
    float mu1s = mu1 * mu1, mu2s = mu2 * mu2, mu12 = mu1 * mu2;
    float s1 = spp - mu1s, s2 = stt - mu2s, s12 = spt - mu12;
    float num = (2.f * mu12 + C1) * (2.f * s12 + C2);
    float den = (mu1s + mu2s + C1) * (s1 + s2 + C2);
    return num * __builtin_amdgcn_rcpf(den);   // |rel err| ~1e-7, fine vs 2e-2 threshold
}

// One wave = one 16-row strip of one image. float4 per lane => wave spans all
// 256 columns. No LDS, no __syncthreads. Horizontal halo via ds_bpermute.
// Vertical 7-tap via modulo-7 register window, loop unrolled by 7 (static idx).
__global__ __launch_bounds__(256) void ssim_main(
    const float* __restrict__ pred,
    const float* __restrict__ targ,
    const float* __restrict__ window,
    float* __restrict__ accbuf)
{
    const int lane = threadIdx.x & 63;
    const int wid  = threadIdx.x >> 6;
    const int gw   = blockIdx.x * 4 + wid;      // 0..2047
    const int n    = gw >> 4;                   // image
    const int s    = gw & 15;                   // strip
    const int r0   = s * ROWS;
    const int c    = lane << 2;

    // exact 1D gaussian from w2d row 3: g[j] = w[21+j] / sum_j w[21+j]
    float g[7];
    {
        float sum = 0.f;
#pragma unroll
        for (int j = 0; j < 7; ++j) { g[j] = window[21 + j]; sum += g[j]; }
        float inv = 1.f / sum;
#pragma unroll
        for (int j = 0; j < 7; ++j) g[j] *= inv;
    }

    const float* pn = pred + (size_t)n * (IMG_H * IMG_W) + c;
    const float* tn = targ + (size_t)n * (IMG_H * IMG_W) + c;

    const int a_up = ((lane - 1) & 63) << 2;
    const int a_dn = ((lane + 1) & 63) << 2;
    const bool l0  = (lane == 0);
    const bool l63 = (lane == 63);

    float4 Whp[7], Wht[7], Wpp[7], Wtt[7], Wpt[7];
    float4 acc = make_float4(0.f, 0.f, 0.f, 0.f);

// horizontal pass for input row J into window slot SLOT
#define HCONV(SLOT, J) { \
    const int j_ = (J); \
    float4 p = make_float4(0.f, 0.f, 0.f, 0.f); \
    float4 t = make_float4(0.f, 0.f, 0.f, 0.f); \
    if ((unsigned)j_ < (unsigned)IMG_H) { \
        p = *(const float4*)(pn + j_ * IMG_W); \
        t = *(const float4*)(tn + j_ * IMG_W); \
    } \
    float pw[10], tw[10]; \
    pw[0] = l0  ? 0.f : pullf(a_up, p.y); \
    pw[1] = l0  ? 0.f : pullf(a_up, p.z); \
    pw[2] = l0  ? 0.f : pullf(a_up, p.w); \
    pw[3] = p.x; pw[4] = p.y; pw[5] = p.z; pw[6] = p.w; \
    pw[7] = l63 ? 0.f : pullf(a_dn, p.x); \
    pw[8] = l63 ? 0.f : pullf(a_dn, p.y); \
    pw[9] = l63 ? 0.f : pullf(a_dn, p.z); \
    tw[0] = l0  ? 0.f : pullf(a_up, t.y); \
    tw[1] = l0  ? 0.f : pullf(a_up, t.z); \
    tw[2] = l0  ? 0.f : pullf(a_up, t.w); \
    tw[3] = t.x; tw[4] = t.y; tw[5] = t.z; tw[6] = t.w; \
    tw[7] = l63 ? 0.f : pullf(a_dn, t.x); \
    tw[8] = l63 ? 0.f : pullf(a_dn, t.y); \
    tw[9] = l63 ? 0.f : pullf(a_dn, t.z); \
    float hp_[4], ht_[4], hpp_[4], htt_[4], hpt_[4]; \
    _Pragma("unroll") \
    for (int i = 0; i < 4; ++i) { \
        float A = 0.f, B = 0.f, Cq = 0.f, D = 0.f, E = 0.f; \
        _Pragma("unroll") \
        for (int k = 0; k < 7; ++k) { \
            float wv = g[k]; \
            float pv = pw[i + k], tv = tw[i + k]; \
            float wp = wv * pv, wt = wv * tv; \
            A += wp; B += wt; \
            Cq = fmaf(wp, pv, Cq); \
            D  = fmaf(wt, tv, D); \
            E  = fmaf(wp, tv, E); \
        } \
        hp_[i] = A; ht_[i] = B; hpp_[i] = Cq; htt_[i] = D; hpt_[i] = E; \
    } \
    Whp[SLOT] = make_float4(hp_[0], hp_[1], hp_[2], hp_[3]); \
    Wht[SLOT] = make_float4(ht_[0], ht_[1], ht_[2], ht_[3]); \
    Wpp[SLOT] = make_float4(hpp_[0], hpp_[1], hpp_[2], hpp_[3]); \
    Wtt[SLOT] = make_float4(htt_[0], htt_[1], htt_[2], htt_[3]); \
    Wpt[SLOT] = make_float4(hpt_[0], hpt_[1], hpt_[2], hpt_[3]); \
}

#define VSTEP(U, K) { \
    const float wv = g[K]; \
    mu1 = f4fma(wv, Whp[((U) + (K)) % 7], mu1); \
    mu2 = f4fma(wv, Wht[((U) + (K)) % 7], mu2); \
    vpp = f4fma(wv, Wpp[((U) + (K)) % 7], vpp); \
    vtt = f4fma(wv, Wtt[((U) + (K)) % 7], vtt); \
    vpt = f4fma(wv, Wpt[((U) + (K)) % 7], vpt); \
}

#define OUTROW(U) { \
    float4 mu1 = make_float4(0.f, 0.f, 0.f, 0.f); \
    float4 mu2 = mu1, vpp = mu1, vtt = mu1, vpt = mu1; \
    VSTEP(U, 0) VSTEP(U, 1) VSTEP(U, 2) VSTEP(U, 3) \
    VSTEP(U, 4) VSTEP(U, 5) VSTEP(U, 6) \
    acc.x += ssim1(mu1.x, mu2.x, vpp.x, vtt.x, vpt.x); \
    acc.y += ssim1(mu1.y, mu2.y, vpp.y, vtt.y, vpt.y); \
    acc.z += ssim1(mu1.z, mu2.z, vpp.z, vtt.z, vpt.z); \
    acc.w += ssim1(mu1.w, mu2.w, vpp.w, vtt.w, vpt.w); \
}

    // prologue: input rows r0-3 .. r0+2 -> slots 0..5
    HCONV(0, r0 - 3) HCONV(1, r0 - 2) HCONV(2, r0 - 1)
    HCONV(3, r0)     HCONV(4, r0 + 1) HCONV(5, r0 + 2)

    // two full chunks of 7 rows (jj = 6..12, 13..19); slot pattern repeats mod 7
#pragma unroll 1
    for (int jb = r0 + 3; jb <= r0 + 10; jb += 7) {
        HCONV(6, jb)     OUTROW(0)
        HCONV(0, jb + 1) OUTROW(1)
        HCONV(1, jb + 2) OUTROW(2)
        HCONV(2, jb + 3) OUTROW(3)
        HCONV(3, jb + 4) OUTROW(4)
        HCONV(4, jb + 5) OUTROW(5)
        HCONV(5, jb + 6) OUTROW(6)
    }
    // tail: jj = 20, 21
    HCONV(6, r0 + 17) OUTROW(0)
    HCONV(0, r0 + 18) OUTROW(1)

    // wave-local reduce, one atomic per wave
    float sum = acc.x + acc.y + acc.z + acc.w;
#pragma unroll
    for (int off = 32; off > 0; off >>= 1)
        sum += __shfl_xor(sum, off, 64);
    if (lane == 0) atomicAdd(accbuf, sum);
}

__global__ void ssim_final(const float* __restrict__ acc, float* __restrict__ out)
{
    out[0] = 1.0f - acc[0] * (1.0f / (128.0f * 256.0f * 256.0f));
}

extern "C" void kernel_launch(void* const* d_in, const int* in_sizes, int n_in,
                              void* d_out, int out_size, void* d_ws, size_t ws_size,
                              hipStream_t stream)
{
    const float* pred   = (const float*)d_in[0];
    const float* targ   = (const float*)d_in[1];
    const float* window = (const float*)d_in[2];
    float* out = (float*)d_out;
    float* acc = (float*)d_ws;

    // d_ws is not re-poisoned between replays: zero the accumulator every call.
    hipMemsetAsync(acc, 0, sizeof(float), stream);

    ssim_main<<<(NIMG * STRIPS) / 4, 256, 0, stream>>>(pred, targ, window, acc);
    ssim_final<<<1, 1, 0, stream>>>(acc, out);
    (void)in_sizes; (void)n_in; (void)out_size; (void)ws_size;
}

// Round 3
// 52.486 us; speedup vs baseline: 1.4640x; 1.4640x over previous
//
#include <hip/hip_runtime.h>

#define IMG_H 256
#define IMG_W 256
#define ROWS 16
#define STRIPS (IMG_H / ROWS)     // 16
#define NIMG 128
#define NWAVES (NIMG * STRIPS)    // 2048 waves, one per 16-row strip

__device__ __forceinline__ float pullf(int addr, float v) {
    return __int_as_float(__builtin_amdgcn_ds_bpermute(addr, __float_as_int(v)));
}

__device__ __forceinline__ float4 f4fma(float w, float4 a, float4 b) {
    return make_float4(fmaf(w, a.x, b.x), fmaf(w, a.y, b.y),
                       fmaf(w, a.z, b.z), fmaf(w, a.w, b.w));
}

__device__ __forceinline__ float ssim1(float mu1, float mu2, float spp, float stt, float spt) {
    const float C1 = 1e-4f, C2 = 9e-4f;
    float mu1s = mu1 * mu1, mu2s = mu2 * mu2, mu12 = mu1 * mu2;
    float s1 = spp - mu1s, s2 = stt - mu2s, s12 = spt - mu12;
    float num = (2.f * mu12 + C1) * (2.f * s12 + C2);
    float den = (mu1s + mu2s + C1) * (s1 + s2 + C2);
    return num / den;                       // exact IEEE divide
}

// One wave = one 16-row strip; float4/lane spans all 256 columns.
// Software-pipelined: row j+1's global loads are issued BEFORE row j's
// bpermute-gather + convolution, so ~600 cyc of VALU hides load latency
// (bpermutes wait on lgkmcnt only; prefetch stays in vmcnt flight).
template<int ATOMIC>
__global__ __launch_bounds__(256) void ssim_main(
    const float* __restrict__ pred,
    const float* __restrict__ targ,
    const float* __restrict__ window,
    float* __restrict__ wsum)
{
    const int lane = threadIdx.x & 63;
    const int wid  = threadIdx.x >> 6;
    const int gw   = blockIdx.x * 4 + wid;  // 0..2047
    const int n    = gw >> 4;
    const int s    = gw & 15;
    const int r0   = s * ROWS;
    const int c    = lane << 2;

    float g[7];
    {
        float sum = 0.f;
#pragma unroll
        for (int j = 0; j < 7; ++j) { g[j] = window[21 + j]; sum += g[j]; }
        float inv = 1.f / sum;
#pragma unroll
        for (int j = 0; j < 7; ++j) g[j] *= inv;
    }

    const float* pn = pred + (size_t)n * (IMG_H * IMG_W) + c;
    const float* tn = targ + (size_t)n * (IMG_H * IMG_W) + c;

    const int a_up = ((lane - 1) & 63) << 2;
    const int a_dn = ((lane + 1) & 63) << 2;
    const bool l0  = (lane == 0);
    const bool l63 = (lane == 63);

    float4 Whp[7], Wht[7], Wpp[7], Wtt[7], Wpt[7];
    float4 acc = make_float4(0.f, 0.f, 0.f, 0.f);
    float4 Pc, Tc, Pn_, Tn_;

#define PLOADI(J, PD, TD) { \
    const int j_ = (J); \
    if ((unsigned)j_ < (unsigned)IMG_H) { \
        PD = *(const float4*)(pn + j_ * IMG_W); \
        TD = *(const float4*)(tn + j_ * IMG_W); \
    } else { \
        PD = make_float4(0.f, 0.f, 0.f, 0.f); \
        TD = make_float4(0.f, 0.f, 0.f, 0.f); \
    } \
}

// gather halo of current row (Pc/Tc) + 5-quantity horizontal conv -> slot
#define GATHER_H(SLOT) { \
    float pw[10], tw[10]; \
    pw[0] = l0  ? 0.f : pullf(a_up, Pc.y); \
    pw[1] = l0  ? 0.f : pullf(a_up, Pc.z); \
    pw[2] = l0  ? 0.f : pullf(a_up, Pc.w); \
    pw[3] = Pc.x; pw[4] = Pc.y; pw[5] = Pc.z; pw[6] = Pc.w; \
    pw[7] = l63 ? 0.f : pullf(a_dn, Pc.x); \
    pw[8] = l63 ? 0.f : pullf(a_dn, Pc.y); \
    pw[9] = l63 ? 0.f : pullf(a_dn, Pc.z); \
    tw[0] = l0  ? 0.f : pullf(a_up, Tc.y); \
    tw[1] = l0  ? 0.f : pullf(a_up, Tc.z); \
    tw[2] = l0  ? 0.f : pullf(a_up, Tc.w); \
    tw[3] = Tc.x; tw[4] = Tc.y; tw[5] = Tc.z; tw[6] = Tc.w; \
    tw[7] = l63 ? 0.f : pullf(a_dn, Tc.x); \
    tw[8] = l63 ? 0.f : pullf(a_dn, Tc.y); \
    tw[9] = l63 ? 0.f : pullf(a_dn, Tc.z); \
    float hA[4], hB[4], hC[4], hD[4], hE[4]; \
    _Pragma("unroll") \
    for (int i = 0; i < 4; ++i) { \
        float A = 0.f, B = 0.f, Cq = 0.f, D = 0.f, E = 0.f; \
        _Pragma("unroll") \
        for (int k = 0; k < 7; ++k) { \
            float wv = g[k]; \
            float pv = pw[i + k], tv = tw[i + k]; \
            float wp = wv * pv, wt = wv * tv; \
            A += wp; B += wt; \
            Cq = fmaf(wp, pv, Cq); \
            D  = fmaf(wt, tv, D); \
            E  = fmaf(wp, tv, E); \
        } \
        hA[i] = A; hB[i] = B; hC[i] = Cq; hD[i] = D; hE[i] = E; \
    } \
    Whp[SLOT] = make_float4(hA[0], hA[1], hA[2], hA[3]); \
    Wht[SLOT] = make_float4(hB[0], hB[1], hB[2], hB[3]); \
    Wpp[SLOT] = make_float4(hC[0], hC[1], hC[2], hC[3]); \
    Wtt[SLOT] = make_float4(hD[0], hD[1], hD[2], hD[3]); \
    Wpt[SLOT] = make_float4(hE[0], hE[1], hE[2], hE[3]); \
}

#define VSTEP(U, K) { \
    const float wv = g[K]; \
    mu1 = f4fma(wv, Whp[((U) + (K)) % 7], mu1); \
    mu2 = f4fma(wv, Wht[((U) + (K)) % 7], mu2); \
    vpp = f4fma(wv, Wpp[((U) + (K)) % 7], vpp); \
    vtt = f4fma(wv, Wtt[((U) + (K)) % 7], vtt); \
    vpt = f4fma(wv, Wpt[((U) + (K)) % 7], vpt); \
}

#define OUTROW(U) { \
    float4 mu1 = make_float4(0.f, 0.f, 0.f, 0.f); \
    float4 mu2 = mu1, vpp = mu1, vtt = mu1, vpt = mu1; \
    VSTEP(U, 0) VSTEP(U, 1) VSTEP(U, 2) VSTEP(U, 3) \
    VSTEP(U, 4) VSTEP(U, 5) VSTEP(U, 6) \
    acc.x += ssim1(mu1.x, mu2.x, vpp.x, vtt.x, vpt.x); \
    acc.y += ssim1(mu1.y, mu2.y, vpp.y, vtt.y, vpt.y); \
    acc.z += ssim1(mu1.z, mu2.z, vpp.z, vtt.z, vpt.z); \
    acc.w += ssim1(mu1.w, mu2.w, vpp.w, vtt.w, vpt.w); \
}

// one pipeline step: prefetch row JNXT, process current row (in Pc/Tc), OUT
#define STEP(SLOT, JNXT, OUTB) { \
    PLOADI(JNXT, Pn_, Tn_); \
    GATHER_H(SLOT); \
    OUTB \
    Pc = Pn_; Tc = Tn_; \
}

    // prologue: load first halo row, then pipeline rows r0-3 .. r0+2
    PLOADI(r0 - 3, Pc, Tc);
    STEP(0, r0 - 2, ;)
    STEP(1, r0 - 1, ;)
    STEP(2, r0,     ;)
    STEP(3, r0 + 1, ;)
    STEP(4, r0 + 2, ;)
    STEP(5, r0 + 3, ;)

    // 2 × 7 steady-state rows (slot pattern repeats mod 7)
#pragma unroll 1
    for (int jb = 0; jb < 2; ++jb) {
        const int base = r0 + 3 + jb * 7;
        STEP(6, base + 1, OUTROW(0))
        STEP(0, base + 2, OUTROW(1))
        STEP(1, base + 3, OUTROW(2))
        STEP(2, base + 4, OUTROW(3))
        STEP(3, base + 5, OUTROW(4))
        STEP(4, base + 6, OUTROW(5))
        STEP(5, base + 7, OUTROW(6))
    }
    // tail: rows r0+17, r0+18 (prefetch target is a dummy re-load, harmless)
    STEP(6, r0 + 18, OUTROW(0))
    STEP(0, r0 + 18, OUTROW(1))

    float sum = acc.x + acc.y + acc.z + acc.w;
#pragma unroll
    for (int off = 32; off > 0; off >>= 1)
        sum += __shfl_xor(sum, off, 64);
    if (lane == 0) {
        if (ATOMIC) atomicAdd(&wsum[0], sum);
        else        wsum[gw] = sum;
    }
#undef PLOADI
#undef GATHER_H
#undef VSTEP
#undef OUTROW
#undef STEP
}

// deterministic f64 tree-reduce of the 2048 per-wave partials
__global__ __launch_bounds__(256) void ssim_final_arr(
    const float* __restrict__ ws, float* __restrict__ out)
{
    __shared__ double sred[4];
    double sm = 0.0;
#pragma unroll
    for (int k = 0; k < NWAVES / 256; ++k)
        sm += (double)ws[threadIdx.x + k * 256];
#pragma unroll
    for (int off = 32; off > 0; off >>= 1)
        sm += __shfl_down(sm, off, 64);
    const int lane = threadIdx.x & 63, wid = threadIdx.x >> 6;
    if (lane == 0) sred[wid] = sm;
    __syncthreads();
    if (threadIdx.x == 0) {
        double tot = sred[0] + sred[1] + sred[2] + sred[3];
        out[0] = (float)(1.0 - tot * (1.0 / (128.0 * 256.0 * 256.0)));
    }
}

__global__ void ssim_final_sc(const float* __restrict__ ws, float* __restrict__ out)
{
    out[0] = 1.0f - ws[0] * (1.0f / (128.0f * 256.0f * 256.0f));
}

extern "C" void kernel_launch(void* const* d_in, const int* in_sizes, int n_in,
                              void* d_out, int out_size, void* d_ws, size_t ws_size,
                              hipStream_t stream)
{
    const float* pred   = (const float*)d_in[0];
    const float* targ   = (const float*)d_in[1];
    const float* window = (const float*)d_in[2];
    float* out = (float*)d_out;
    float* ws  = (float*)d_ws;

    if (ws_size >= NWAVES * sizeof(float)) {
        // every ws slot is written by the grid each call: no memset needed
        ssim_main<0><<<NWAVES / 4, 256, 0, stream>>>(pred, targ, window, ws);
        ssim_final_arr<<<1, 256, 0, stream>>>(ws, out);
    } else {
        hipMemsetAsync(ws, 0, sizeof(float), stream);
        ssim_main<1><<<NWAVES / 4, 256, 0, stream>>>(pred, targ, window, ws);
        ssim_final_sc<<<1, 1, 0, stream>>>(ws, out);
    }
    (void)in_sizes; (void)n_in; (void)out_size;
}